// Round 15
// baseline (816.385 us; speedup 1.0000x reference)
//
#include <hip/hip_runtime.h>
#include <math.h>

// fp32 ws layout (floats), proven (R2/R7/R13):
#define OFF0 0
#define OFF1 18432
#define OFF2 83968
#define OFF3 149504
#define OFF4 215040
#define OFFB 216064

__global__ void prep_params(
    const float* __restrict__ w0, const float* __restrict__ w1,
    const float* __restrict__ w2, const float* __restrict__ w3,
    const float* __restrict__ w4,
    const float* __restrict__ m0, const float* __restrict__ m1,
    const float* __restrict__ m2, const float* __restrict__ m3,
    const float* __restrict__ m4,
    float* __restrict__ ws)
{
    int idx = blockIdx.x * blockDim.x + threadIdx.x;
    if (idx >= 2056) return;
    int layer, b, o;
    if (idx < 2048) { layer = idx >> 9; b = (idx >> 7) & 3; o = idx & 127; }
    else { layer = 4; int r = idx - 2048; b = r >> 1; o = r & 1; }

    const float* w; const float* m; int Fm, O, Fp; int off;
    switch (layer) {
      case 0:  w = w0; m = m0; Fm = 35;  O = 128; Fp = 36;  off = OFF0; break;
      case 1:  w = w1; m = m1; Fm = 128; O = 128; Fp = 128; off = OFF1; break;
      case 2:  w = w2; m = m2; Fm = 128; O = 128; Fp = 128; off = OFF2; break;
      case 3:  w = w3; m = m3; Fm = 128; O = 128; Fp = 128; off = OFF3; break;
      default: w = w4; m = m4; Fm = 128; O = 2;   Fp = 128; off = OFF4; break;
    }

    float ss = 0.f;
    for (int f = 0; f < Fm; ++f) {
        float v = w[f * O + o] * m[(b * Fm + f) * O + o];
        ss += v * v;
    }
    float r = 1.0f / fmaxf(sqrtf(ss), 1e-12f);

    float* pT = ws + off + (b * O + o) * Fp;
    for (int f = 0; f < Fm; ++f) {
        float v = w[f * O + o] * m[(b * Fm + f) * O + o];
        pT[f] = v * r;
    }
    if (layer == 0) pT[35] = 0.f;           // zero-pad fan-in 35 -> 36
    ws[OFFB + layer * 512 + b * 128 + o] = w[Fm * O + o];
}

// Launder a (wave-uniform) pointer into a VGPR pair so the compiler cannot
// prove uniformity -> weight reads become global_load_dwordx4 (vmcnt-tracked,
// in-order, deep software pipelining) instead of s_load (lgkmcnt(0) drains
// that serialize against ds_read every k-step).
__device__ __forceinline__ const float* vlaunder(const float* p) {
    unsigned long long u = (unsigned long long)p;
    asm("" : "+v"(u));
    return (const float*)u;
}

// Two points (rows r0, r1 sharing swizzle salt s) x 8 outputs over F inputs.
// Weights via VMEM broadcast loads (laundered base + imm offsets, all <4KB);
// hidden via swizzled ds_read_b128 (R13-proven conflict-free).
template<int F>
__device__ __forceinline__ void accum2p(const float* __restrict__ r0,
                                        const float* __restrict__ r1, int s,
                                        const float* __restrict__ pb_u,
                                        const float* __restrict__ bs,
                                        float* a0, float* a1)
{
    const float* pb = vlaunder(pb_u);
    #pragma unroll
    for (int j = 0; j < 8; ++j) { a0[j] = bs[j]; a1[j] = bs[j]; }
    #pragma unroll 2
    for (int k = 0; k < (F + 3) / 4; ++k) {
        const int off = ((k ^ s) << 2);
        float4 h0 = *(const float4*)(r0 + off);
        float4 h1 = *(const float4*)(r1 + off);
        #pragma unroll
        for (int j = 0; j < 8; ++j) {
            float4 wv4 = *(const float4*)(pb + j * F + k * 4);   // global_load_dwordx4
            a0[j] = fmaf(h0.x, wv4.x, a0[j]);  a1[j] = fmaf(h1.x, wv4.x, a1[j]);
            a0[j] = fmaf(h0.y, wv4.y, a0[j]);  a1[j] = fmaf(h1.y, wv4.y, a1[j]);
            a0[j] = fmaf(h0.z, wv4.z, a0[j]);  a1[j] = fmaf(h1.z, wv4.z, a1[j]);
            a0[j] = fmaf(h0.w, wv4.w, a0[j]);  a1[j] = fmaf(h1.w, wv4.w, a1[j]);
        }
    }
}

__device__ __forceinline__ float4 interp_pt(const float* __restrict__ lat,
                                            int b, int pg, int c0)
{
    const int y = pg >> 8, x = pg & 255;
    const float sy = (y + 0.5f) * 0.25f - 0.5f;
    const float sx = (x + 0.5f) * 0.25f - 0.5f;
    const float fy = floorf(sy), fx = floorf(sx);
    const float ty = sy - fy, tx = sx - fx;
    int y0 = (int)fy, x0 = (int)fx;
    const int y1 = min(y0 + 1, 63); y0 = max(y0, 0);
    const int x1 = min(x0 + 1, 63); x0 = max(x0, 0);
    const float* base = lat + ((size_t)b << 17) + c0;
    const float4 v00 = *(const float4*)(base + (y0 * 64 + x0) * 32);
    const float4 v01 = *(const float4*)(base + (y0 * 64 + x1) * 32);
    const float4 v10 = *(const float4*)(base + (y1 * 64 + x0) * 32);
    const float4 v11 = *(const float4*)(base + (y1 * 64 + x1) * 32);
    const float w00 = (1.f - ty) * (1.f - tx), w01 = (1.f - ty) * tx;
    const float w10 = ty * (1.f - tx),         w11 = ty * tx;
    float4 r;
    r.x = w00 * v00.x + w01 * v01.x + w10 * v10.x + w11 * v11.x;
    r.y = w00 * v00.y + w01 * v01.y + w10 * v10.y + w11 * v11.y;
    r.z = w00 * v00.z + w01 * v01.z + w10 * v10.z + w11 * v11.z;
    r.w = w00 * v00.w + w01 * v01.w + w10 * v10.w + w11 * v11.w;
    return r;
}

__global__ __launch_bounds__(512, 4)
void hyponet_main(const float* __restrict__ coord,
                  const float* __restrict__ lat,
                  const float* __restrict__ ws,
                  float* __restrict__ out)
{
    __shared__ float hsf[128 * 128];   // 64 KB: 128 points x 32 swizzled float4-groups
    const int tid  = threadIdx.x;
    const int lane = tid & 63;
    const int wv   = tid >> 6;               // 8 waves: o-block owner
    const int b    = blockIdx.x >> 9;        // 512 tiles per batch
    const int tile = blockIdx.x & 511;
    const int pg0  = tile * 128 + lane;      // this lane's two points
    const int pg1  = pg0 + 64;
    const int s    = lane & 31;              // swizzle salt (rows lane, lane+64 share it)
    float* r0 = hsf + lane * 128;
    float* r1 = r0 + 64 * 128;

    // ---- bilinear upsample + coord for both points
    {
        const int c0 = wv * 4;               // group k = wv
        *(float4*)(r0 + (((wv) ^ s) << 2)) = interp_pt(lat, b, pg0, c0);
        *(float4*)(r1 + (((wv) ^ s) << 2)) = interp_pt(lat, b, pg1, c0);
        if (wv == 0) {                       // group 8: {c0,c1,c2,0}
            const float* cp0 = coord + ((size_t)b * 65536 + pg0) * 3;
            const float* cp1 = coord + ((size_t)b * 65536 + pg1) * 3;
            *(float4*)(r0 + ((8 ^ s) << 2)) = make_float4(cp0[0], cp0[1], cp0[2], 0.f);
            *(float4*)(r1 + ((8 ^ s) << 2)) = make_float4(cp1[0], cp1[1], cp1[2], 0.f);
        }
    }
    __syncthreads();

    const int ob0 = __builtin_amdgcn_readfirstlane(wv * 16);
    const int ob1 = __builtin_amdgcn_readfirstlane(wv * 16 + 8);
    float a0[16], a1[16];

    // ---- layer 0: 36 -> 128, sin
    {
        accum2p<36>(r0, r1, s, ws + OFF0 + (b * 128 + ob0) * 36,
                    ws + OFFB + b * 128 + ob0, a0, a1);
        accum2p<36>(r0, r1, s, ws + OFF0 + (b * 128 + ob1) * 36,
                    ws + OFFB + b * 128 + ob1, a0 + 8, a1 + 8);
        #pragma unroll
        for (int j = 0; j < 16; ++j) { a0[j] = __sinf(a0[j]); a1[j] = __sinf(a1[j]); }
        __syncthreads();
        #pragma unroll
        for (int jj = 0; jj < 4; ++jj) {
            const int off = (((wv * 4 + jj) ^ s) << 2);
            *(float4*)(r0 + off) = make_float4(a0[jj*4], a0[jj*4+1], a0[jj*4+2], a0[jj*4+3]);
            *(float4*)(r1 + off) = make_float4(a1[jj*4], a1[jj*4+1], a1[jj*4+2], a1[jj*4+3]);
        }
        __syncthreads();
    }

    // ---- layers 1..3: 129 -> 128, sin
    #pragma unroll 1
    for (int L = 1; L <= 3; ++L) {
        const int off_w = (L == 1) ? OFF1 : (L == 2) ? OFF2 : OFF3;
        accum2p<128>(r0, r1, s, ws + off_w + (b * 128 + ob0) * 128,
                     ws + OFFB + L * 512 + b * 128 + ob0, a0, a1);
        accum2p<128>(r0, r1, s, ws + off_w + (b * 128 + ob1) * 128,
                     ws + OFFB + L * 512 + b * 128 + ob1, a0 + 8, a1 + 8);
        #pragma unroll
        for (int j = 0; j < 16; ++j) { a0[j] = __sinf(a0[j]); a1[j] = __sinf(a1[j]); }
        __syncthreads();
        #pragma unroll
        for (int jj = 0; jj < 4; ++jj) {
            const int off = (((wv * 4 + jj) ^ s) << 2);
            *(float4*)(r0 + off) = make_float4(a0[jj*4], a0[jj*4+1], a0[jj*4+2], a0[jj*4+3]);
            *(float4*)(r1 + off) = make_float4(a1[jj*4], a1[jj*4+1], a1[jj*4+2], a1[jj*4+3]);
        }
        __syncthreads();
    }

    // ---- layer 4: 129 -> 2, linear; waves 0 (points 0..63) and 1 (64..127)
    if (wv < 2) {
        const float* hl = (wv == 0) ? r0 : r1;   // row salt == s for both
        const float* pb = vlaunder(ws + OFF4 + b * 2 * 128);
        const float* bs = ws + OFFB + 4 * 512 + b * 128;
        float q0 = bs[0], q1 = bs[1];
        #pragma unroll 2
        for (int k = 0; k < 32; ++k) {
            float4 h = *(const float4*)(hl + ((k ^ s) << 2));
            float4 w0r = *(const float4*)(pb + k * 4);          // row o=0
            float4 w1r = *(const float4*)(pb + 128 + k * 4);    // row o=1
            q0 = fmaf(h.x, w0r.x, q0); q1 = fmaf(h.x, w1r.x, q1);
            q0 = fmaf(h.y, w0r.y, q0); q1 = fmaf(h.y, w1r.y, q1);
            q0 = fmaf(h.z, w0r.z, q0); q1 = fmaf(h.z, w1r.z, q1);
            q0 = fmaf(h.w, w0r.w, q0); q1 = fmaf(h.w, w1r.w, q1);
        }
        const int pt = tile * 128 + wv * 64 + lane;
        *(float2*)&out[((size_t)b * 65536 + pt) * 2] = make_float2(q0, q1);
    }
}

extern "C" void kernel_launch(void* const* d_in, const int* in_sizes, int n_in,
                              void* d_out, int out_size, void* d_ws, size_t ws_size,
                              hipStream_t stream)
{
    const float* coord = (const float*)d_in[0];
    const float* lat   = (const float*)d_in[1];
    float* ws = (float*)d_ws;

    prep_params<<<9, 256, 0, stream>>>(
        (const float*)d_in[2], (const float*)d_in[3], (const float*)d_in[4],
        (const float*)d_in[5], (const float*)d_in[6],
        (const float*)d_in[7], (const float*)d_in[8], (const float*)d_in[9],
        (const float*)d_in[10], (const float*)d_in[11], ws);

    hyponet_main<<<2048, 512, 0, stream>>>(coord, lat, ws, (float*)d_out);
}

// Round 16
// 357.581 us; speedup vs baseline: 2.2831x; 2.2831x over previous
//
#include <hip/hip_runtime.h>
#include <math.h>

typedef __attribute__((ext_vector_type(2))) float f2;
typedef __attribute__((ext_vector_type(4))) float f4;

// fp32 ws layout (floats), proven (R2/R7/R13):
#define OFF0 0
#define OFF1 18432
#define OFF2 83968
#define OFF3 149504
#define OFF4 215040
#define OFFB 216064

__global__ void prep_params(
    const float* __restrict__ w0, const float* __restrict__ w1,
    const float* __restrict__ w2, const float* __restrict__ w3,
    const float* __restrict__ w4,
    const float* __restrict__ m0, const float* __restrict__ m1,
    const float* __restrict__ m2, const float* __restrict__ m3,
    const float* __restrict__ m4,
    float* __restrict__ ws)
{
    int idx = blockIdx.x * blockDim.x + threadIdx.x;
    if (idx >= 2056) return;
    int layer, b, o;
    if (idx < 2048) { layer = idx >> 9; b = (idx >> 7) & 3; o = idx & 127; }
    else { layer = 4; int r = idx - 2048; b = r >> 1; o = r & 1; }

    const float* w; const float* m; int Fm, O, Fp; int off;
    switch (layer) {
      case 0:  w = w0; m = m0; Fm = 35;  O = 128; Fp = 36;  off = OFF0; break;
      case 1:  w = w1; m = m1; Fm = 128; O = 128; Fp = 128; off = OFF1; break;
      case 2:  w = w2; m = m2; Fm = 128; O = 128; Fp = 128; off = OFF2; break;
      case 3:  w = w3; m = m3; Fm = 128; O = 128; Fp = 128; off = OFF3; break;
      default: w = w4; m = m4; Fm = 128; O = 2;   Fp = 128; off = OFF4; break;
    }

    float ss = 0.f;
    for (int f = 0; f < Fm; ++f) {
        float v = w[f * O + o] * m[(b * Fm + f) * O + o];
        ss += v * v;
    }
    float r = 1.0f / fmaxf(sqrtf(ss), 1e-12f);

    float* pT = ws + off + (b * O + o) * Fp;
    for (int f = 0; f < Fm; ++f) {
        float v = w[f * O + o] * m[(b * Fm + f) * O + o];
        pT[f] = v * r;
    }
    if (layer == 0) pT[35] = 0.f;           // zero-pad fan-in 35 -> 36
    ws[OFFB + layer * 512 + b * 128 + o] = w[Fm * O + o];
}

// Two points (rows r0, r1 sharing swizzle salt s) x 8 outputs over F inputs.
// PACKED fp32: acc pairs accumulate (even-k, odd-k) partials via v_pk_fma_f32;
// hidden k-pairs are sub-pairs of the ds_read_b128 quad, weight k-pairs are
// SGPR sub-pairs of the s_load_dwordx4 (1 SGPR operand per VALU instr: legal).
// Horizontal add happens in the caller (a = acc.x + acc.y).
template<int F>
__device__ __forceinline__ void accum2p(const float* __restrict__ r0,
                                        const float* __restrict__ r1, int s,
                                        const float* __restrict__ pb,
                                        const float* __restrict__ bs,
                                        f2* a0, f2* a1)
{
    #pragma unroll
    for (int j = 0; j < 8; ++j) {
        a0[j].x = bs[j]; a0[j].y = 0.f;
        a1[j].x = bs[j]; a1[j].y = 0.f;
    }
    #pragma unroll 2
    for (int k = 0; k < (F + 3) / 4; ++k) {
        const int off = ((k ^ s) << 2);
        f4 h0 = *(const f4*)(r0 + off);   // ds_read_b128, conflict-free (R13-proven)
        f4 h1 = *(const f4*)(r1 + off);
        #pragma unroll
        for (int j = 0; j < 8; ++j) {
            const f4 w = *(const f4*)(pb + j * F + k * 4);   // s_load_dwordx4
            a0[j] = __builtin_elementwise_fma(h0.xy, w.xy, a0[j]);
            a0[j] = __builtin_elementwise_fma(h0.zw, w.zw, a0[j]);
            a1[j] = __builtin_elementwise_fma(h1.xy, w.xy, a1[j]);
            a1[j] = __builtin_elementwise_fma(h1.zw, w.zw, a1[j]);
        }
    }
}

__device__ __forceinline__ float4 interp_pt(const float* __restrict__ lat,
                                            int b, int pg, int c0)
{
    const int y = pg >> 8, x = pg & 255;
    const float sy = (y + 0.5f) * 0.25f - 0.5f;
    const float sx = (x + 0.5f) * 0.25f - 0.5f;
    const float fy = floorf(sy), fx = floorf(sx);
    const float ty = sy - fy, tx = sx - fx;
    int y0 = (int)fy, x0 = (int)fx;
    const int y1 = min(y0 + 1, 63); y0 = max(y0, 0);
    const int x1 = min(x0 + 1, 63); x0 = max(x0, 0);
    const float* base = lat + ((size_t)b << 17) + c0;
    const float4 v00 = *(const float4*)(base + (y0 * 64 + x0) * 32);
    const float4 v01 = *(const float4*)(base + (y0 * 64 + x1) * 32);
    const float4 v10 = *(const float4*)(base + (y1 * 64 + x0) * 32);
    const float4 v11 = *(const float4*)(base + (y1 * 64 + x1) * 32);
    const float w00 = (1.f - ty) * (1.f - tx), w01 = (1.f - ty) * tx;
    const float w10 = ty * (1.f - tx),         w11 = ty * tx;
    float4 r;
    r.x = w00 * v00.x + w01 * v01.x + w10 * v10.x + w11 * v11.x;
    r.y = w00 * v00.y + w01 * v01.y + w10 * v10.y + w11 * v11.y;
    r.z = w00 * v00.z + w01 * v01.z + w10 * v10.z + w11 * v11.z;
    r.w = w00 * v00.w + w01 * v01.w + w10 * v10.w + w11 * v11.w;
    return r;
}

__global__ __launch_bounds__(512, 4)
void hyponet_main(const float* __restrict__ coord,
                  const float* __restrict__ lat,
                  const float* __restrict__ ws,
                  float* __restrict__ out)
{
    __shared__ float hsf[128 * 128];   // 64 KB: 128 points x 32 swizzled float4-groups
    const int tid  = threadIdx.x;
    const int lane = tid & 63;
    const int wv   = tid >> 6;               // 8 waves: o-block owner
    const int b    = blockIdx.x >> 9;        // 512 tiles per batch
    const int tile = blockIdx.x & 511;
    const int pg0  = tile * 128 + lane;      // this lane's two points
    const int pg1  = pg0 + 64;
    const int s    = lane & 31;              // swizzle salt (rows lane, lane+64 share it)
    float* r0 = hsf + lane * 128;
    float* r1 = r0 + 64 * 128;

    // ---- bilinear upsample + coord for both points
    {
        const int c0 = wv * 4;               // group k = wv
        *(float4*)(r0 + (((wv) ^ s) << 2)) = interp_pt(lat, b, pg0, c0);
        *(float4*)(r1 + (((wv) ^ s) << 2)) = interp_pt(lat, b, pg1, c0);
        if (wv == 0) {                       // group 8: {c0,c1,c2,0}
            const float* cp0 = coord + ((size_t)b * 65536 + pg0) * 3;
            const float* cp1 = coord + ((size_t)b * 65536 + pg1) * 3;
            *(float4*)(r0 + ((8 ^ s) << 2)) = make_float4(cp0[0], cp0[1], cp0[2], 0.f);
            *(float4*)(r1 + ((8 ^ s) << 2)) = make_float4(cp1[0], cp1[1], cp1[2], 0.f);
        }
    }
    __syncthreads();

    const int ob0 = __builtin_amdgcn_readfirstlane(wv * 16);
    const int ob1 = __builtin_amdgcn_readfirstlane(wv * 16 + 8);
    f2 a0[16], a1[16];
    float v0[16], v1[16];

    // ---- layer 0: 36 -> 128, sin
    {
        accum2p<36>(r0, r1, s, ws + OFF0 + (b * 128 + ob0) * 36,
                    ws + OFFB + b * 128 + ob0, a0, a1);
        accum2p<36>(r0, r1, s, ws + OFF0 + (b * 128 + ob1) * 36,
                    ws + OFFB + b * 128 + ob1, a0 + 8, a1 + 8);
        #pragma unroll
        for (int j = 0; j < 16; ++j) {
            v0[j] = __sinf(a0[j].x + a0[j].y);
            v1[j] = __sinf(a1[j].x + a1[j].y);
        }
        __syncthreads();
        #pragma unroll
        for (int jj = 0; jj < 4; ++jj) {
            const int off = (((wv * 4 + jj) ^ s) << 2);
            *(float4*)(r0 + off) = make_float4(v0[jj*4], v0[jj*4+1], v0[jj*4+2], v0[jj*4+3]);
            *(float4*)(r1 + off) = make_float4(v1[jj*4], v1[jj*4+1], v1[jj*4+2], v1[jj*4+3]);
        }
        __syncthreads();
    }

    // ---- layers 1..3: 129 -> 128, sin
    #pragma unroll 1
    for (int L = 1; L <= 3; ++L) {
        const int off_w = (L == 1) ? OFF1 : (L == 2) ? OFF2 : OFF3;
        accum2p<128>(r0, r1, s, ws + off_w + (b * 128 + ob0) * 128,
                     ws + OFFB + L * 512 + b * 128 + ob0, a0, a1);
        accum2p<128>(r0, r1, s, ws + off_w + (b * 128 + ob1) * 128,
                     ws + OFFB + L * 512 + b * 128 + ob1, a0 + 8, a1 + 8);
        #pragma unroll
        for (int j = 0; j < 16; ++j) {
            v0[j] = __sinf(a0[j].x + a0[j].y);
            v1[j] = __sinf(a1[j].x + a1[j].y);
        }
        __syncthreads();
        #pragma unroll
        for (int jj = 0; jj < 4; ++jj) {
            const int off = (((wv * 4 + jj) ^ s) << 2);
            *(float4*)(r0 + off) = make_float4(v0[jj*4], v0[jj*4+1], v0[jj*4+2], v0[jj*4+3]);
            *(float4*)(r1 + off) = make_float4(v1[jj*4], v1[jj*4+1], v1[jj*4+2], v1[jj*4+3]);
        }
        __syncthreads();
    }

    // ---- layer 4: 129 -> 2, linear; waves 0 (points 0..63) and 1 (64..127)
    if (wv < 2) {
        const float* hl = (wv == 0) ? r0 : r1;   // row salt == s for both
        const float* pb = ws + OFF4 + b * 2 * 128;
        const float* bs = ws + OFFB + 4 * 512 + b * 128;
        f2 q0; q0.x = bs[0]; q0.y = 0.f;
        f2 q1; q1.x = bs[1]; q1.y = 0.f;
        #pragma unroll 2
        for (int k = 0; k < 32; ++k) {
            f4 h = *(const f4*)(hl + ((k ^ s) << 2));
            const f4 w0r = *(const f4*)(pb + k * 4);          // row o=0
            const f4 w1r = *(const f4*)(pb + 128 + k * 4);    // row o=1
            q0 = __builtin_elementwise_fma(h.xy, w0r.xy, q0);
            q0 = __builtin_elementwise_fma(h.zw, w0r.zw, q0);
            q1 = __builtin_elementwise_fma(h.xy, w1r.xy, q1);
            q1 = __builtin_elementwise_fma(h.zw, w1r.zw, q1);
        }
        const int pt = tile * 128 + wv * 64 + lane;
        *(float2*)&out[((size_t)b * 65536 + pt) * 2] =
            make_float2(q0.x + q0.y, q1.x + q1.y);
    }
}

extern "C" void kernel_launch(void* const* d_in, const int* in_sizes, int n_in,
                              void* d_out, int out_size, void* d_ws, size_t ws_size,
                              hipStream_t stream)
{
    const float* coord = (const float*)d_in[0];
    const float* lat   = (const float*)d_in[1];
    float* ws = (float*)d_ws;

    prep_params<<<9, 256, 0, stream>>>(
        (const float*)d_in[2], (const float*)d_in[3], (const float*)d_in[4],
        (const float*)d_in[5], (const float*)d_in[6],
        (const float*)d_in[7], (const float*)d_in[8], (const float*)d_in[9],
        (const float*)d_in[10], (const float*)d_in[11], ws);

    hyponet_main<<<2048, 512, 0, stream>>>(coord, lat, ws, (float*)d_out);
}